// Round 3
// baseline (91.240 us; speedup 1.0000x reference)
//
#include <hip/hip_runtime.h>
#include <math.h>

// ---------------- problem constants ----------------
#define NROWS 4096
#define DIM   512
#define BM    128
#define BN    128
#define KSTEPS (DIM / 32)         // 16 K-steps of 32
#define NSLOT 32                  // col-block partial slots per row

typedef __bf16 bf16x8 __attribute__((ext_vector_type(8)));
typedef float  f32x4  __attribute__((ext_vector_type(4)));

#define GL16(G, L) __builtin_amdgcn_global_load_lds( \
    (const __attribute__((address_space(1))) void*)(G), \
    (__attribute__((address_space(3))) void*)(L), 16, 0, 0)

// ---------------- kernel 1: row-normalize to bf16 (4 rows/block) ----------------
__global__ __launch_bounds__(256)
void normalize_kernel(const float* __restrict__ X, const float* __restrict__ Y,
                      __bf16* __restrict__ Xn, __bf16* __restrict__ Yn)
{
    const int wid  = threadIdx.x >> 6;
    const int lane = threadIdx.x & 63;
    const int row  = blockIdx.x * 4 + wid;
    const float* src = blockIdx.y ? Y : X;
    __bf16*      dst = blockIdx.y ? Yn : Xn;

    const float4* s4 = reinterpret_cast<const float4*>(src + (size_t)row * DIM);
    float4 v0 = s4[lane * 2 + 0];
    float4 v1 = s4[lane * 2 + 1];
    float ss = v0.x*v0.x + v0.y*v0.y + v0.z*v0.z + v0.w*v0.w
             + v1.x*v1.x + v1.y*v1.y + v1.z*v1.z + v1.w*v1.w;
    #pragma unroll
    for (int m = 1; m < 64; m <<= 1) ss += __shfl_xor(ss, m);
    const float scale = 1.0f / fmaxf(sqrtf(ss), 1e-8f);

    bf16x8 o;
    o[0] = (__bf16)(v0.x * scale); o[1] = (__bf16)(v0.y * scale);
    o[2] = (__bf16)(v0.z * scale); o[3] = (__bf16)(v0.w * scale);
    o[4] = (__bf16)(v1.x * scale); o[5] = (__bf16)(v1.y * scale);
    o[6] = (__bf16)(v1.z * scale); o[7] = (__bf16)(v1.w * scale);
    *reinterpret_cast<bf16x8*>(dst + (size_t)row * DIM + lane * 8) = o;
}

// ---------------- kernel 2: fused gram + exp-sum partials ----------------
// Swapped-operand MFMA: C[j, i], j lane-local. Logits a=-simT, b=-simP in [-1,1]
// -> plain sums S=sum e^a, U=sum e^a a, V=sum e^a b, Q=sum e^b (mergeable).
// J-panels: LDS 3-stage rotation, counted vmcnt. I-frags: direct global (L2-hot).
__global__ __launch_bounds__(256, 2)
void gram_kl_kernel(const __bf16* __restrict__ Xn, const __bf16* __restrict__ Yn,
                    float4* __restrict__ partials)
{
    // 3 stages x [J_X 8KB | J_Y 8KB] = 48 KiB
    __shared__ char lds[3][16384];
    __shared__ float4 scr[2][4][16];   // epilogue cross-wave combine

    const int tid  = threadIdx.x;
    const int wid  = tid >> 6;
    const int lane = tid & 63;

    // XCD-pinned mapping: bi == blockIdx (mod 8) -> same-bi blocks share an XCD L2
    const int g  = blockIdx.x;
    const int bi = (g & 7) + 8 * ((g >> 3) & 3);   // bits 0-4
    const int bj = g >> 5;                          // bits 5-9
    const int i0 = bi * BM;
    const int j0 = bj * BN;

    const int wi = wid >> 1;   // i-half (0..1)
    const int wj = wid & 1;    // j-half (0..1)

    // staging source offsets (pre-swizzled global, linear LDS dest)
    const int u0 = tid, u1 = tid + 256;
    const int so0 = ((u0 >> 2) << 10) + (((u0 & 3) ^ ((u0 >> 3) & 3)) << 4);
    const int so1 = ((u1 >> 2) << 10) + (((u1 & 3) ^ ((u1 >> 3) & 3)) << 4);
    const int d0 = wid * 1024;
    const int d1 = 4096 + wid * 1024;

    const char* bx = (const char*)Xn;
    const char* by = (const char*)Yn;

    auto STAGE = [&](int st, int ks) {
        const size_t joff = ((size_t)j0 << 10) + ((size_t)ks << 6);
        char* l = &lds[st][0];
        GL16(bx + joff + so0, l + d0);
        GL16(bx + joff + so1, l + d1);
        GL16(by + joff + so0, l + 8192 + d0);
        GL16(by + joff + so1, l + 8192 + d1);
    };

    // J fragment read offset (swizzled)
    const int rd_off = ((lane & 15) << 6) + ((((lane >> 4) ^ ((lane >> 1) & 3))) << 4);

    // I fragment global base: row = i0 + wi*64 + fi*16 + (lane&15), seg = lane>>4
    const size_t ibase = ((size_t)(i0 + wi * 64 + (lane & 15)) << 10) + ((size_t)(lane >> 4) << 4);

    f32x4 accT[4][4];  // [fj][fi]
    f32x4 accP[4][4];
    #pragma unroll
    for (int fj = 0; fj < 4; ++fj)
        #pragma unroll
        for (int fi = 0; fi < 4; ++fi) {
            accT[fj][fi] = f32x4{0.f, 0.f, 0.f, 0.f};
            accP[fj][fi] = f32x4{0.f, 0.f, 0.f, 0.f};
        }

    STAGE(0, 0);
    STAGE(1, 1);

    for (int s = 0; s < KSTEPS; ++s) {
        // buf[s%3] complete when <=4 stage-loads outstanding (FIFO, per-wave)
        if (s < KSTEPS - 1) {
            asm volatile("s_waitcnt vmcnt(4)" ::: "memory");
        } else {
            asm volatile("s_waitcnt vmcnt(0)" ::: "memory");
        }
        __builtin_amdgcn_s_barrier();

        // 1) I-frags direct from global (oldest vmem ops of this step)
        bf16x8 bXf[4], bYf[4];
        const char* pI = (const char*)0;
        #pragma unroll
        for (int fi = 0; fi < 4; ++fi) {
            const size_t off = ibase + ((size_t)fi << 14) + ((size_t)s << 6);
            bXf[fi] = *reinterpret_cast<const bf16x8*>(bx + off);
            bYf[fi] = *reinterpret_cast<const bf16x8*>(by + off);
        }
        (void)pI;

        // 2) J-frags from LDS (swizzled reads)
        const char* l = &lds[s % 3][0];
        bf16x8 aX[4], aY[4];
        #pragma unroll
        for (int fj = 0; fj < 4; ++fj) {
            const int fo = ((wj * 4 + fj) << 10) + rd_off;
            aX[fj] = *reinterpret_cast<const bf16x8*>(l + fo);
            aY[fj] = *reinterpret_cast<const bf16x8*>(l + 8192 + fo);
        }

        // 3) prefetch stage s+2 (youngest vmem ops -> counted wait skips them)
        if (s + 2 < KSTEPS) STAGE((s + 2) % 3, s + 2);

        // 4) MFMA (compiler waits: lgkm for aX/aY, vmcnt(<=4) for bXf/bYf)
        #pragma unroll
        for (int fj = 0; fj < 4; ++fj)
            #pragma unroll
            for (int fi = 0; fi < 4; ++fi) {
                accT[fj][fi] = __builtin_amdgcn_mfma_f32_16x16x32_bf16(aX[fj], bXf[fi], accT[fj][fi], 0, 0, 0);
                accP[fj][fi] = __builtin_amdgcn_mfma_f32_16x16x32_bf16(aY[fj], bYf[fi], accP[fj][fi], 0, 0, 0);
            }
    }

    // ---- fold: 32 similarity pairs per lane -> 4 sums per fi ----
    float4 res[4];
    #pragma unroll
    for (int fi = 0; fi < 4; ++fi) {
        float S = 0.f, U = 0.f, V = 0.f, Q = 0.f;
        #pragma unroll
        for (int fj = 0; fj < 4; ++fj)
            #pragma unroll
            for (int r = 0; r < 4; ++r) {
                const float a = -accT[fj][fi][r];
                const float b = -accP[fj][fi][r];
                const float ea = __expf(a);
                const float eb = __expf(b);
                S += ea; U += ea * a; V += ea * b; Q += eb;
            }
        #pragma unroll
        for (int m = 16; m <= 32; m <<= 1) {
            S += __shfl_xor(S, m);
            U += __shfl_xor(U, m);
            V += __shfl_xor(V, m);
            Q += __shfl_xor(Q, m);
        }
        res[fi] = float4{S, U, V, Q};
    }

    // combine wj halves through LDS scratch, write one slot per (row, bj)
    if (wj == 1 && lane < 16) {
        #pragma unroll
        for (int fi = 0; fi < 4; ++fi) scr[wi][fi][lane] = res[fi];
    }
    __syncthreads();
    if (wj == 0 && lane < 16) {
        #pragma unroll
        for (int fi = 0; fi < 4; ++fi) {
            const float4 o = scr[wi][fi][lane];
            const int row = i0 + wi * 64 + fi * 16 + lane;
            partials[(size_t)row * NSLOT + bj] =
                float4{res[fi].x + o.x, res[fi].y + o.y, res[fi].z + o.z, res[fi].w + o.w};
        }
    }
}

// ---------------- kernel 3: merge partial sums -> per-row KL, block-reduce ----------------
__global__ __launch_bounds__(256)
void merge_kernel(const float4* __restrict__ partials, float* __restrict__ blocksum)
{
    __shared__ float w[4];
    const int row = blockIdx.x * 256 + threadIdx.x;
    float S = 0.f, U = 0.f, V = 0.f, Q = 0.f;
    #pragma unroll
    for (int s = 0; s < NSLOT; ++s) {
        const float4 p = partials[(size_t)row * NSLOT + s];
        S += p.x; U += p.y; V += p.z; Q += p.w;
    }
    float kl = (U - V) / S - logf(S) + logf(Q);
    #pragma unroll
    for (int m = 1; m < 64; m <<= 1) kl += __shfl_xor(kl, m);
    if ((threadIdx.x & 63) == 0) w[threadIdx.x >> 6] = kl;
    __syncthreads();
    if (threadIdx.x == 0) blocksum[blockIdx.x] = w[0] + w[1] + w[2] + w[3];
}

// ---------------- kernel 4: final mean ----------------
__global__ __launch_bounds__(64)
void reduce_kernel(const float* __restrict__ blocksum, float* __restrict__ out)
{
    float v = (threadIdx.x < 16) ? blocksum[threadIdx.x] : 0.f;
    #pragma unroll
    for (int m = 1; m < 16; m <<= 1) v += __shfl_xor(v, m);
    if (threadIdx.x == 0) out[0] = v / (float)NROWS;
}

// ---------------- launch ----------------
extern "C" void kernel_launch(void* const* d_in, const int* in_sizes, int n_in,
                              void* d_out, int out_size, void* d_ws, size_t ws_size,
                              hipStream_t stream)
{
    const float* X = (const float*)d_in[0];   // cosine_distance_latent (target)
    const float* Y = (const float*)d_in[1];   // mse_latent (predicted)
    float* out = (float*)d_out;

    char* ws = (char*)d_ws;
    const size_t mat_bytes = (size_t)NROWS * DIM * sizeof(__bf16);          // 4 MiB each
    __bf16* Xn = (__bf16*)ws;
    __bf16* Yn = (__bf16*)(ws + mat_bytes);
    float4* partials = (float4*)(ws + 2 * mat_bytes);                       // 4096*32*16 B = 2 MiB
    float* blocksum = (float*)(ws + 2 * mat_bytes + (size_t)NROWS * NSLOT * sizeof(float4));

    normalize_kernel<<<dim3(NROWS / 4, 2), 256, 0, stream>>>(X, Y, Xn, Yn);
    gram_kl_kernel<<<(NROWS / BM) * (NROWS / BN), 256, 0, stream>>>(Xn, Yn, partials);
    merge_kernel<<<NROWS / 256, 256, 0, stream>>>(partials, blocksum);
    reduce_kernel<<<1, 64, 0, stream>>>(blocksum, out);
}

// Round 4
// 60.090 us; speedup vs baseline: 1.5184x; 1.5184x over previous
//
#include <hip/hip_runtime.h>
#include <math.h>

// ---------------- problem constants ----------------
#define NROWS 4096
#define DIM   512
#define BMI   256                 // i-rows per block
#define BNJ   128                 // j-rows per block
#define KSTEPS (DIM / 32)         // 16 K-steps of 32
#define NSLOT (NROWS / BNJ)       // 32 partial slots per row
#define STB   49152               // bytes per LDS stage (4 panels: IX 16K, IY 16K, JX 8K, JY 8K)

typedef __bf16 bf16x8 __attribute__((ext_vector_type(8)));
typedef float  f32x4  __attribute__((ext_vector_type(4)));

#define GL16(G, L) __builtin_amdgcn_global_load_lds( \
    (const __attribute__((address_space(1))) void*)(G), \
    (__attribute__((address_space(3))) void*)(L), 16, 0, 0)

// ---------------- kernel 1: row-normalize to bf16 (4 rows/block) ----------------
__global__ __launch_bounds__(256)
void normalize_kernel(const float* __restrict__ X, const float* __restrict__ Y,
                      __bf16* __restrict__ Xn, __bf16* __restrict__ Yn)
{
    const int wid  = threadIdx.x >> 6;
    const int lane = threadIdx.x & 63;
    const int row  = blockIdx.x * 4 + wid;
    const float* src = blockIdx.y ? Y : X;
    __bf16*      dst = blockIdx.y ? Yn : Xn;

    const float4* s4 = reinterpret_cast<const float4*>(src + (size_t)row * DIM);
    float4 v0 = s4[lane * 2 + 0];
    float4 v1 = s4[lane * 2 + 1];
    float ss = v0.x*v0.x + v0.y*v0.y + v0.z*v0.z + v0.w*v0.w
             + v1.x*v1.x + v1.y*v1.y + v1.z*v1.z + v1.w*v1.w;
    #pragma unroll
    for (int m = 1; m < 64; m <<= 1) ss += __shfl_xor(ss, m);
    const float scale = 1.0f / fmaxf(sqrtf(ss), 1e-8f);

    bf16x8 o;
    o[0] = (__bf16)(v0.x * scale); o[1] = (__bf16)(v0.y * scale);
    o[2] = (__bf16)(v0.z * scale); o[3] = (__bf16)(v0.w * scale);
    o[4] = (__bf16)(v1.x * scale); o[5] = (__bf16)(v1.y * scale);
    o[6] = (__bf16)(v1.z * scale); o[7] = (__bf16)(v1.w * scale);
    *reinterpret_cast<bf16x8*>(dst + (size_t)row * DIM + lane * 8) = o;
}

// ---------------- kernel 2: fused gram + exp-sum partials ----------------
// 8 waves: m = wid>>2 selects matrix (0: X/target, 1: Y/pred); q = wid&3 is the
// quadrant (iq = q&1 over 2x128 i-rows, jq = q>>1 over 2x64 j-rows). Each wave is a
// single-matrix 128i x 64j MFMA tile (swapped operands: C[j,i], j lane-local).
// All panels staged via global_load_lds, 3-stage rotation, counted vmcnt (never 0
// mid-loop). Epilogue: P-waves dump accs to LDS; T-waves pair elementwise and fold
// S = sum e^a, U = sum e^a*a, V = sum e^a*b, Q = sum e^b  (a=-simT, b=-simP in [-1,1],
// so no max tracking needed; sums mergeable across blocks).
__global__ __launch_bounds__(512, 2)
void gram_kl_kernel(const __bf16* __restrict__ Xn, const __bf16* __restrict__ Yn,
                    float4* __restrict__ partials)
{
    __shared__ char lds[3 * STB];   // 144 KiB; epilogue aliases into it after the loop

    const int tid  = threadIdx.x;
    const int wid  = tid >> 6;
    const int lane = tid & 63;
    const int m  = wid >> 2;       // matrix select
    const int q  = wid & 3;
    const int iq = q & 1;
    const int jq = q >> 1;

    // XCD tiling: xcd = g&7 owns a 4bi x 16bj region; per generation 4bi x 8bj (~4MB L2)
    const int g = blockIdx.x;
    const int x = g & 7;
    const int t = g >> 3;          // 0..63
    const int bi = (x & 3) * 4 + (t & 3);                       // 0..15
    const int bj = (x >> 2) * 16 + ((t >> 2) & 7) + (t >> 5) * 8; // 0..31
    const int i0 = bi * BMI;
    const int j0 = bj * BNJ;

    // ---- staging source offsets (pre-swizzled global, linear LDS dest) ----
    // 16B unit u: row = u>>2, slot = u&3 holds global seg = slot ^ ((row>>1)&3)
    const int xnib = (((tid & 3) ^ ((tid >> 3) & 3)) << 4);
    const size_t so_i0 = ((size_t)(i0 + (tid >> 2)) << 10) + xnib;
    const size_t so_i1 = so_i0 + ((size_t)128 << 10);
    const size_t so_j  = ((size_t)(j0 + (tid >> 2)) << 10) + xnib;
    const int wbase = wid * 1024;   // wave-uniform LDS dest base within an 8KB issue region

    const char* bx = (const char*)Xn;
    const char* by = (const char*)Yn;

    auto STAGE = [&](int st, int ks) {
        char* base = &lds[st * STB];
        const size_t ko = (size_t)ks << 6;
        GL16(bx + so_i0 + ko, base + 0 * 8192 + wbase);   // I_X rows 0..127
        GL16(bx + so_i1 + ko, base + 1 * 8192 + wbase);   // I_X rows 128..255
        GL16(by + so_i0 + ko, base + 2 * 8192 + wbase);   // I_Y
        GL16(by + so_i1 + ko, base + 3 * 8192 + wbase);
        GL16(bx + so_j  + ko, base + 4 * 8192 + wbase);   // J_X rows 0..127
        GL16(by + so_j  + ko, base + 5 * 8192 + wbase);   // J_Y
    };

    // swizzled fragment read offset: row-part + xor'd 16B segment
    const int rdx = ((lane & 15) << 6) + ((((lane >> 4) ^ ((lane >> 1) & 3))) << 4);
    const int ibase = m * 16384 + iq * 8192;          // my I panel (+fi*1024)
    const int jbase = 32768 + m * 8192 + jq * 4096;   // my J panel (+fj*1024)

    f32x4 acc[4][8];   // [fj][fi]
    #pragma unroll
    for (int fj = 0; fj < 4; ++fj)
        #pragma unroll
        for (int fi = 0; fi < 8; ++fi)
            acc[fj][fi] = f32x4{0.f, 0.f, 0.f, 0.f};

    STAGE(0, 0);
    STAGE(1, 1);

    for (int s = 0; s < KSTEPS; ++s) {
        // own stage-s DMAs complete (6 of stage s+1 may remain in flight)
        if (s < KSTEPS - 1) asm volatile("s_waitcnt vmcnt(6)" ::: "memory");
        else                asm volatile("s_waitcnt vmcnt(0)" ::: "memory");
        __builtin_amdgcn_s_barrier();          // now ALL waves' stage-s DMAs complete
        asm volatile("" ::: "memory");         // pin LDS reads below the barrier

        const char* base = &lds[(s % 3) * STB];
        bf16x8 aJ[4], bI[8];
        #pragma unroll
        for (int fj = 0; fj < 4; ++fj)
            aJ[fj] = *reinterpret_cast<const bf16x8*>(base + jbase + fj * 1024 + rdx);
        #pragma unroll
        for (int fi = 0; fi < 8; ++fi)
            bI[fi] = *reinterpret_cast<const bf16x8*>(base + ibase + fi * 1024 + rdx);

        if (s + 2 < KSTEPS) STAGE((s + 2) % 3, s + 2);   // depth-2 prefetch

        #pragma unroll
        for (int fj = 0; fj < 4; ++fj)
            #pragma unroll
            for (int fi = 0; fi < 8; ++fi)
                acc[fj][fi] = __builtin_amdgcn_mfma_f32_16x16x32_bf16(aJ[fj], bI[fi], acc[fj][fi], 0, 0, 0);
    }

    // ---------------- epilogue ----------------
    __syncthreads();
    if (m == 1) {   // P-waves dump raw similarity accs (32KB per wave, 128KB total)
        char* dst = &lds[q * 32768 + lane * 16];
        #pragma unroll
        for (int fj = 0; fj < 4; ++fj)
            #pragma unroll
            for (int fi = 0; fi < 8; ++fi)
                *reinterpret_cast<f32x4*>(dst + (fj * 8 + fi) * 1024) = acc[fj][fi];
    }
    __syncthreads();

    float4 res[8];
    if (m == 0) {   // T-waves pair elementwise with matching P-wave and fold
        const char* src = &lds[q * 32768 + lane * 16];
        #pragma unroll
        for (int fi = 0; fi < 8; ++fi) {
            float S = 0.f, U = 0.f, V = 0.f, Q = 0.f;
            #pragma unroll
            for (int fj = 0; fj < 4; ++fj) {
                const f32x4 pb = *reinterpret_cast<const f32x4*>(src + (fj * 8 + fi) * 1024);
                #pragma unroll
                for (int r = 0; r < 4; ++r) {
                    const float a = -acc[fj][fi][r];
                    const float b = -pb[r];
                    const float ea = __expf(a);
                    const float eb = __expf(b);
                    S += ea; U += ea * a; V += ea * b; Q += eb;
                }
            }
            #pragma unroll
            for (int mm = 16; mm <= 32; mm <<= 1) {
                S += __shfl_xor(S, mm);
                U += __shfl_xor(U, mm);
                V += __shfl_xor(V, mm);
                Q += __shfl_xor(Q, mm);
            }
            res[fi] = float4{S, U, V, Q};
        }
        // jq=1 waves publish their half-block j-sums
        if (jq == 1 && lane < 16) {
            float4* scr = reinterpret_cast<float4*>(&lds[131072]);
            #pragma unroll
            for (int fi = 0; fi < 8; ++fi)
                scr[(iq * 8 + fi) * 16 + lane] = res[fi];
        }
    }
    __syncthreads();
    if (m == 0 && jq == 0 && lane < 16) {
        const float4* scr = reinterpret_cast<const float4*>(&lds[131072]);
        #pragma unroll
        for (int fi = 0; fi < 8; ++fi) {
            const float4 o = scr[(iq * 8 + fi) * 16 + lane];
            const int row = i0 + iq * 128 + fi * 16 + lane;
            partials[(size_t)row * NSLOT + bj] =
                float4{res[fi].x + o.x, res[fi].y + o.y, res[fi].z + o.z, res[fi].w + o.w};
        }
    }
}

// ---------------- kernel 3: merge partial sums -> per-row KL, block-reduce ----------------
__global__ __launch_bounds__(256)
void merge_kernel(const float4* __restrict__ partials, float* __restrict__ blocksum)
{
    __shared__ float w[4];
    const int row = blockIdx.x * 256 + threadIdx.x;
    float S = 0.f, U = 0.f, V = 0.f, Q = 0.f;
    #pragma unroll
    for (int s = 0; s < NSLOT; ++s) {
        const float4 p = partials[(size_t)row * NSLOT + s];
        S += p.x; U += p.y; V += p.z; Q += p.w;
    }
    float kl = (U - V) / S - logf(S) + logf(Q);
    #pragma unroll
    for (int mm = 1; mm < 64; mm <<= 1) kl += __shfl_xor(kl, mm);
    if ((threadIdx.x & 63) == 0) w[threadIdx.x >> 6] = kl;
    __syncthreads();
    if (threadIdx.x == 0) blocksum[blockIdx.x] = w[0] + w[1] + w[2] + w[3];
}

// ---------------- kernel 4: final mean ----------------
__global__ __launch_bounds__(64)
void reduce_kernel(const float* __restrict__ blocksum, float* __restrict__ out)
{
    float v = (threadIdx.x < 16) ? blocksum[threadIdx.x] : 0.f;
    #pragma unroll
    for (int mm = 1; mm < 16; mm <<= 1) v += __shfl_xor(v, mm);
    if (threadIdx.x == 0) out[0] = v / (float)NROWS;
}

// ---------------- launch ----------------
extern "C" void kernel_launch(void* const* d_in, const int* in_sizes, int n_in,
                              void* d_out, int out_size, void* d_ws, size_t ws_size,
                              hipStream_t stream)
{
    const float* X = (const float*)d_in[0];   // cosine_distance_latent (target)
    const float* Y = (const float*)d_in[1];   // mse_latent (predicted)
    float* out = (float*)d_out;

    char* ws = (char*)d_ws;
    const size_t mat_bytes = (size_t)NROWS * DIM * sizeof(__bf16);          // 4 MiB each
    __bf16* Xn = (__bf16*)ws;
    __bf16* Yn = (__bf16*)(ws + mat_bytes);
    float4* partials = (float4*)(ws + 2 * mat_bytes);                       // 4096*32*16 B = 2 MiB
    float* blocksum = (float*)(ws + 2 * mat_bytes + (size_t)NROWS * NSLOT * sizeof(float4));

    normalize_kernel<<<dim3(NROWS / 4, 2), 256, 0, stream>>>(X, Y, Xn, Yn);
    gram_kl_kernel<<<(NROWS / BMI) * (NROWS / BNJ), 512, 0, stream>>>(Xn, Yn, partials);
    merge_kernel<<<NROWS / 256, 256, 0, stream>>>(partials, blocksum);
    reduce_kernel<<<1, 64, 0, stream>>>(blocksum, out);
}